// Round 3
// baseline (2251.614 us; speedup 1.0000x reference)
//
#include <hip/hip_runtime.h>
#include <hip/hip_bf16.h>
#include <math.h>
#include <stdint.h>

// Problem constants
#define T_TOK 4096
#define H_DIM 2880
#define E_NUM 16
#define ALPHA 1.702f
#define EPS_RMS 1e-5f

// GEMM tiling (8-phase template, 512 threads = 8 waves 4Mx2N)
#define PADM 256
#define BK 64
#define NKT (H_DIM / BK)      // 45
#define MAX_RT 80             // sum ceil(cnt_e/256) <= 79
#define MAX_ROWS (MAX_RT * PADM)   // 20480
#define NCT1 30               // gemm1: col tiles of 96 (gate) + 96 (lin)
#define NCT2 15               // gemm2: col tiles of 192
#define G1 (MAX_RT * NCT1)    // 2400 (div 8)
#define G2 (MAX_RT * NCT2)    // 1200 (div 8)
#define LBUF 57344            // per LDS buffer: A 32K @0, B 24K @32768

typedef __attribute__((ext_vector_type(8))) short short8;
typedef __attribute__((ext_vector_type(4))) float f32x4;

__device__ __forceinline__ unsigned short f2bf(float f) {
  unsigned u = __float_as_uint(f);
  return (unsigned short)((u + 0x7fffu + ((u >> 16) & 1u)) >> 16);
}
__device__ __forceinline__ unsigned pk2(float a, float b) {
  return (unsigned)f2bf(a) | ((unsigned)f2bf(b) << 16);
}
__device__ __forceinline__ void gl_lds16(const void* g, unsigned char* lds_dst) {
  __builtin_amdgcn_global_load_lds(
      (const __attribute__((address_space(1))) void*)g,
      (__attribute__((address_space(3))) void*)lds_dst, 16, 0, 0);
}
#define BARS() do { __builtin_amdgcn_s_barrier(); __builtin_amdgcn_sched_barrier(0); } while (0)
#define DRAIN() asm volatile("s_waitcnt vmcnt(0) lgkmcnt(0)" ::: "memory")

// ---------------- K1: rmsnorm + residual copy + fp32 gate + top4 ----------------
__global__ __launch_bounds__(256) void k_norm_gate(
    const float* __restrict__ x, const float* __restrict__ norm_w,
    const float* __restrict__ gate_w, const float* __restrict__ gate_b,
    float* __restrict__ out, unsigned short* __restrict__ t_out,
    int* __restrict__ topk_id, float* __restrict__ topk_w,
    int* __restrict__ counts)
{
  int t = blockIdx.x, tid = threadIdx.x;
  const float4* xr = (const float4*)(x + (size_t)t * H_DIM);
  float4* outr = (float4*)(out + (size_t)t * H_DIM);
  float4 xa[3];
  float ss = 0.f;
  int j = 0;
  for (int i = tid; i < 720; i += 256, j++) {
    float4 v = xr[i]; xa[j] = v; outr[i] = v;    // residual: out = x
    ss += v.x * v.x + v.y * v.y + v.z * v.z + v.w * v.w;
  }
#pragma unroll
  for (int o = 1; o < 64; o <<= 1) ss += __shfl_xor(ss, o, 64);
  __shared__ float red[4];
  if ((tid & 63) == 0) red[tid >> 6] = ss;
  __syncthreads();
  float rs = rsqrtf((red[0] + red[1] + red[2] + red[3]) * (1.f / H_DIM) + EPS_RMS);

  float part[16];
#pragma unroll
  for (int q = 0; q < 16; q++) part[q] = 0.f;
  j = 0;
  for (int i = tid; i < 720; i += 256, j++) {
    float4 v = xa[j];
    float4 w = ((const float4*)norm_w)[i];
    float t0 = v.x * rs * w.x, t1 = v.y * rs * w.y;
    float t2 = v.z * rs * w.z, t3 = v.w * rs * w.w;
    ushort4 b; b.x = f2bf(t0); b.y = f2bf(t1); b.z = f2bf(t2); b.w = f2bf(t3);
    ((ushort4*)(t_out + (size_t)t * H_DIM))[i] = b;
#pragma unroll
    for (int q = 0; q < 16; q++) {    // fp32 logits (selection accuracy)
      float4 g = ((const float4*)(gate_w + (size_t)q * H_DIM))[i];
      part[q] += t0 * g.x + t1 * g.y + t2 * g.z + t3 * g.w;
    }
  }
  __shared__ float lg[4][16];
#pragma unroll
  for (int q = 0; q < 16; q++) {
    float p = part[q];
#pragma unroll
    for (int o = 1; o < 64; o <<= 1) p += __shfl_xor(p, o, 64);
    if ((tid & 63) == 0) lg[tid >> 6][q] = p;
  }
  __syncthreads();
  if (tid == 0) {
    float logit[16];
    for (int q = 0; q < 16; q++)
      logit[q] = lg[0][q] + lg[1][q] + lg[2][q] + lg[3][q] + gate_b[q];
    unsigned used = 0; int idx[4]; float val[4];
    for (int k = 0; k < 4; k++) {           // ties -> lowest index
      float best = -3.4e38f; int bi = 0;
      for (int q = 0; q < 16; q++)
        if (!((used >> q) & 1u) && logit[q] > best) { best = logit[q]; bi = q; }
      used |= 1u << bi; idx[k] = bi; val[k] = best;
    }
    float s0 = 0.f, w4[4];
    for (int k = 0; k < 4; k++) { w4[k] = expf(val[k] - val[0]); s0 += w4[k]; }
    for (int k = 0; k < 4; k++) {
      topk_id[t * 4 + k] = idx[k];
      topk_w[t * 4 + k] = w4[k] / s0;
      atomicAdd(&counts[idx[k]], 1);
    }
  }
}

// ---------------- K2a: padded prefix offsets ----------------
__global__ void k_offsets(const int* __restrict__ counts, int* __restrict__ d_off) {
  if (threadIdx.x == 0) {
    int acc = 0;
    for (int q = 0; q < 16; q++) {
      d_off[q] = acc;
      acc += ((counts[q] + PADM - 1) / PADM) * PADM;
    }
    d_off[16] = acc;
  }
}

// ---------------- K2b: deterministic token-ordered routing lists ----------------
__global__ __launch_bounds__(256) void k_fill(
    const int* __restrict__ topk_id, const float* __restrict__ topk_w,
    const int* __restrict__ counts, const int* __restrict__ d_off,
    int* __restrict__ perm_tok, float* __restrict__ perm_w)
{
  int e = blockIdx.x;
  int base = d_off[e], pe = d_off[e + 1] - base, cnt = counts[e];
  int tid = threadIdx.x, lane = tid & 63, wv = tid >> 6;
  __shared__ int wsum[4];
  int pos = 0;
  for (int c0 = 0; c0 < T_TOK; c0 += 256) {
    int tok = c0 + tid;
    int4 ids = ((const int4*)topk_id)[tok];
    int flag = 0, slot = 0;
    if (ids.x == e) { flag = 1; slot = 0; }
    else if (ids.y == e) { flag = 1; slot = 1; }
    else if (ids.z == e) { flag = 1; slot = 2; }
    else if (ids.w == e) { flag = 1; slot = 3; }
    unsigned long long b = __ballot(flag);
    int wprefix = __popcll(b & ((1ULL << lane) - 1ULL));
    if (lane == 0) wsum[wv] = __popcll(b);
    __syncthreads();
    int woff = 0;
    for (int i = 0; i < wv; i++) woff += wsum[i];
    int tot = wsum[0] + wsum[1] + wsum[2] + wsum[3];
    if (flag) {
      int p = base + pos + woff + wprefix;
      perm_tok[p] = tok;
      perm_w[p] = topk_w[tok * 4 + slot];
    }
    pos += tot;
    __syncthreads();
  }
  for (int i = cnt + tid; i < pe; i += 256) {   // padding rows: token 0, weight 0
    perm_tok[base + i] = 0;
    perm_w[base + i] = 0.f;
  }
}

// ================= K3: grouped gemm1, 8-phase schedule =================
// BM=256, cols: 96 gate + 96 lin, BK=64. 8 waves 4Mx2N; per wave 64r x (48g+48l).
// LDS/buf: A[256][128B] @0 (linear dst for gload_lds, src pre-swizzled),
//          Bg[96][128B] @32768, Bl[96][128B] @45056 (ds_write dst-swizzled).
// slot s of row r holds k-chunk s^(r&7); r&7 == lane&7 for all frag reads.
#define PH_G1(H, MH, STAGE, POST)                                                   \
  {                                                                                 \
    const unsigned char* Ab = lds + cur * LBUF;                                     \
    int r0 = wm * 64 + (MH) * 32 + lr;                                              \
    unsigned ko = (unsigned)((((H) * 4 + lh) ^ S) << 4);                            \
    short8 a0 = *(const short8*)(Ab + r0 * 128 + ko);                               \
    short8 a1 = *(const short8*)(Ab + (r0 + 16) * 128 + ko);                        \
    if ((MH) == 0) {                                                                \
      _Pragma("unroll")                                                             \
      for (int nf = 0; nf < 3; nf++) {                                              \
        unsigned bo = (unsigned)((wn * 48 + nf * 16 + lr) * 128) + ko;              \
        bgf[nf] = *(const short8*)(Ab + 32768 + bo);                                \
        blf[nf] = *(const short8*)(Ab + 45056 + bo);                                \
      }                                                                             \
    }                                                                               \
    STAGE;                                                                          \
    BARS();                                                                         \
    __builtin_amdgcn_s_setprio(1);                                                  \
    _Pragma("unroll")                                                               \
    for (int nf = 0; nf < 3; nf++) {                                                \
      acc[0][(MH)*2][nf]   = __builtin_amdgcn_mfma_f32_16x16x32_bf16(a0, bgf[nf], acc[0][(MH)*2][nf], 0, 0, 0);   \
      acc[0][(MH)*2+1][nf] = __builtin_amdgcn_mfma_f32_16x16x32_bf16(a1, bgf[nf], acc[0][(MH)*2+1][nf], 0, 0, 0); \
      acc[1][(MH)*2][nf]   = __builtin_amdgcn_mfma_f32_16x16x32_bf16(a0, blf[nf], acc[1][(MH)*2][nf], 0, 0, 0);   \
      acc[1][(MH)*2+1][nf] = __builtin_amdgcn_mfma_f32_16x16x32_bf16(a1, blf[nf], acc[1][(MH)*2+1][nf], 0, 0, 0); \
    }                                                                               \
    __builtin_amdgcn_s_setprio(0);                                                  \
    POST;                                                                           \
    BARS();                                                                         \
  }

#define G1_ST_BLOAD do { if (st) {                                                  \
  _Pragma("unroll")                                                                 \
  for (int j = 0; j < 3; j++) {                                                     \
    bv[j][0] = bptr[j][(kt + 1) * 16];                                              \
    bv[j][1] = bptr[j][(kt + 1) * 16 + 1];                                          \
  } } } while (0)

#define G1_ST_AGLD do { if (st) {                                                   \
  _Pragma("unroll")                                                                 \
  for (int i = 0; i < 4; i++)                                                       \
    gl_lds16(aptr[i] + (size_t)(kt + 1) * BK, lds + nxt * LBUF + adst[i]);          \
  } } while (0)

#define G1_ST_BPACK do { if (st) {                                                  \
  _Pragma("unroll")                                                                 \
  for (int j = 0; j < 3; j++) {                                                     \
    uint4 p;                                                                        \
    p.x = pk2(bv[j][0].x, bv[j][0].y); p.y = pk2(bv[j][0].z, bv[j][0].w);           \
    p.z = pk2(bv[j][1].x, bv[j][1].y); p.w = pk2(bv[j][1].z, bv[j][1].w);           \
    *(uint4*)(lds + nxt * LBUF + bdst[j]) = p;                                      \
  } } } while (0)

__global__ __launch_bounds__(512, 2) void k_gemm1(
    const unsigned short* __restrict__ t_bf16,
    const float* __restrict__ w1, const float* __restrict__ b1,
    const int* __restrict__ perm_tok, const int* __restrict__ d_off,
    unsigned short* __restrict__ act)
{
  __shared__ __align__(16) unsigned char lds[2 * LBUF];
  const int total = d_off[16];
  int bid = blockIdx.x;
  int wg = (bid & 7) * (G1 / 8) + (bid >> 3);   // XCD-chunked, rt fastest
  int ct = wg / MAX_RT, rt = wg % MAX_RT;
  int rowbase = rt * PADM;
  if (rowbase >= total) return;
  int e = 0;
#pragma unroll
  for (int q = 0; q < E_NUM; q++) if (d_off[q + 1] <= rowbase) e = q + 1;

  int tid = threadIdx.x, lane = tid & 63;
  int wv = tid >> 6, wm = wv & 3, wn = wv >> 2;
  int lr = lane & 15, lh = lane >> 4, S = lane & 7;

  // A staging: gload_lds linear dst, pre-swizzled source chunk
  const unsigned short* aptr[4]; unsigned adst[4];
#pragma unroll
  for (int i = 0; i < 4; i++) {
    int ch = tid + 512 * i;                 // 0..2047
    int r = ch >> 3, c = ch & 7;
    int tok = perm_tok[rowbase + r];
    aptr[i] = t_bf16 + (size_t)tok * H_DIM + ((c ^ (r & 7)) * 8);
    adst[i] = (unsigned)ch * 16;
  }
  // B staging: linear fp32 source, dst-swizzled ds_write
  const float4* bptr[3]; unsigned bdst[3];
#pragma unroll
  for (int j = 0; j < 3; j++) {
    int ch = tid + 512 * j;                 // 0..1535
    int half = ch >= 768;
    int rr = (ch - half * 768) >> 3, c = ch & 7;
    size_t grow = (size_t)e * (2 * H_DIM) + (size_t)(ct * 96 + rr) + (size_t)half * H_DIM;
    bptr[j] = (const float4*)(w1 + grow * H_DIM) + c * 2;
    bdst[j] = (unsigned)(32768 + half * 12288 + rr * 128 + ((c ^ (rr & 7)) << 4));
  }

  f32x4 zero = {0.f, 0.f, 0.f, 0.f};
  f32x4 acc[2][4][3];
#pragma unroll
  for (int p = 0; p < 2; p++)
#pragma unroll
    for (int m = 0; m < 4; m++)
#pragma unroll
      for (int n = 0; n < 3; n++) acc[p][m][n] = zero;

  short8 bgf[3], blf[3];
  float4 bv[3][2];

  // prologue: stage kt=0 into buf0
#pragma unroll
  for (int j = 0; j < 3; j++) { bv[j][0] = bptr[j][0]; bv[j][1] = bptr[j][1]; }
#pragma unroll
  for (int i = 0; i < 4; i++) gl_lds16(aptr[i], lds + adst[i]);
#pragma unroll
  for (int j = 0; j < 3; j++) {
    uint4 p;
    p.x = pk2(bv[j][0].x, bv[j][0].y); p.y = pk2(bv[j][0].z, bv[j][0].w);
    p.z = pk2(bv[j][1].x, bv[j][1].y); p.w = pk2(bv[j][1].z, bv[j][1].w);
    *(uint4*)(lds + bdst[j]) = p;
  }
  DRAIN();
  BARS();

#pragma unroll 1
  for (int kt = 0; kt < NKT; kt++) {
    int cur = kt & 1, nxt = cur ^ 1;
    bool st = (kt + 1 < NKT);
    PH_G1(0, 0, G1_ST_BLOAD, );
    PH_G1(0, 1, G1_ST_AGLD, );
    PH_G1(1, 0, G1_ST_BPACK, );
    PH_G1(1, 1, , DRAIN());
  }

  // epilogue: bias + SwiGLU, store act bf16
#pragma unroll
  for (int mf = 0; mf < 4; mf++) {
    int row0 = rowbase + wm * 64 + mf * 16 + lh * 4;
#pragma unroll
    for (int nf = 0; nf < 3; nf++) {
      int col = ct * 96 + wn * 48 + nf * 16 + lr;
      float bg = b1[(size_t)e * (2 * H_DIM) + col];
      float bl = b1[(size_t)e * (2 * H_DIM) + H_DIM + col];
#pragma unroll
      for (int j = 0; j < 4; j++) {
        float g = acc[0][mf][nf][j] + bg;
        float l = acc[1][mf][nf][j] + bl;
        float s = 1.f / (1.f + __expf(-ALPHA * g));
        act[(size_t)(row0 + j) * H_DIM + col] = f2bf(g * s * (l + 1.f));
      }
    }
  }
}

// ================= K4: grouped gemm2, 8-phase schedule =================
// BM=256, BN=192, BK=64. Per wave 64r x 96c (6 n-frags). B region 24KB @32768.
#define PH_G2(H, MH, STAGE, POST)                                                   \
  {                                                                                 \
    const unsigned char* Ab = lds + cur * LBUF;                                     \
    int r0 = wm * 64 + (MH) * 32 + lr;                                              \
    unsigned ko = (unsigned)((((H) * 4 + lh) ^ S) << 4);                            \
    short8 a0 = *(const short8*)(Ab + r0 * 128 + ko);                               \
    short8 a1 = *(const short8*)(Ab + (r0 + 16) * 128 + ko);                        \
    if ((MH) == 0) {                                                                \
      _Pragma("unroll")                                                             \
      for (int nf = 0; nf < 6; nf++) {                                              \
        unsigned bo = (unsigned)((wn * 96 + nf * 16 + lr) * 128) + ko;              \
        bf[nf] = *(const short8*)(Ab + 32768 + bo);                                 \
      }                                                                             \
    }                                                                               \
    STAGE;                                                                          \
    BARS();                                                                         \
    __builtin_amdgcn_s_setprio(1);                                                  \
    _Pragma("unroll")                                                               \
    for (int nf = 0; nf < 6; nf++) {                                                \
      acc[(MH)*2][nf]   = __builtin_amdgcn_mfma_f32_16x16x32_bf16(a0, bf[nf], acc[(MH)*2][nf], 0, 0, 0);   \
      acc[(MH)*2+1][nf] = __builtin_amdgcn_mfma_f32_16x16x32_bf16(a1, bf[nf], acc[(MH)*2+1][nf], 0, 0, 0); \
    }                                                                               \
    __builtin_amdgcn_s_setprio(0);                                                  \
    POST;                                                                           \
    BARS();                                                                         \
  }

__global__ __launch_bounds__(512, 2) void k_gemm2(
    const unsigned short* __restrict__ act,
    const float* __restrict__ w2, const float* __restrict__ b2,
    const int* __restrict__ perm_tok, const float* __restrict__ perm_w,
    const int* __restrict__ d_off,
    float* __restrict__ out)
{
  __shared__ __align__(16) unsigned char lds[2 * LBUF];
  __shared__ int stok[PADM]; __shared__ float swt[PADM];
  const int total = d_off[16];
  int bid = blockIdx.x;
  int wg = (bid & 7) * (G2 / 8) + (bid >> 3);
  int ct = wg / MAX_RT, rt = wg % MAX_RT;
  int rowbase = rt * PADM;
  if (rowbase >= total) return;
  int e = 0;
#pragma unroll
  for (int q = 0; q < E_NUM; q++) if (d_off[q + 1] <= rowbase) e = q + 1;

  int tid = threadIdx.x, lane = tid & 63;
  int wv = tid >> 6, wm = wv & 3, wn = wv >> 2;
  int lr = lane & 15, lh = lane >> 4, S = lane & 7;

  if (tid < PADM) { stok[tid] = perm_tok[rowbase + tid]; swt[tid] = perm_w[rowbase + tid]; }

  const unsigned short* aptr[4]; unsigned adst[4];
#pragma unroll
  for (int i = 0; i < 4; i++) {
    int ch = tid + 512 * i;
    int r = ch >> 3, c = ch & 7;
    aptr[i] = act + (size_t)(rowbase + r) * H_DIM + ((c ^ (r & 7)) * 8);
    adst[i] = (unsigned)ch * 16;
  }
  const float4* bptr[3]; unsigned bdst[3];
#pragma unroll
  for (int j = 0; j < 3; j++) {
    int ch = tid + 512 * j;
    int rr = ch >> 3, c = ch & 7;
    size_t grow = (size_t)e * H_DIM + (size_t)(ct * 192 + rr);
    bptr[j] = (const float4*)(w2 + grow * H_DIM) + c * 2;
    bdst[j] = (unsigned)(32768 + rr * 128 + ((c ^ (rr & 7)) << 4));
  }

  f32x4 zero = {0.f, 0.f, 0.f, 0.f};
  f32x4 acc[4][6];
#pragma unroll
  for (int m = 0; m < 4; m++)
#pragma unroll
    for (int n = 0; n < 6; n++) acc[m][n] = zero;

  short8 bf[6];
  float4 bv[3][2];

#pragma unroll
  for (int j = 0; j < 3; j++) { bv[j][0] = bptr[j][0]; bv[j][1] = bptr[j][1]; }
#pragma unroll
  for (int i = 0; i < 4; i++) gl_lds16(aptr[i], lds + adst[i]);
#pragma unroll
  for (int j = 0; j < 3; j++) {
    uint4 p;
    p.x = pk2(bv[j][0].x, bv[j][0].y); p.y = pk2(bv[j][0].z, bv[j][0].w);
    p.z = pk2(bv[j][1].x, bv[j][1].y); p.w = pk2(bv[j][1].z, bv[j][1].w);
    *(uint4*)(lds + bdst[j]) = p;
  }
  DRAIN();
  BARS();

#pragma unroll 1
  for (int kt = 0; kt < NKT; kt++) {
    int cur = kt & 1, nxt = cur ^ 1;
    bool st = (kt + 1 < NKT);
    PH_G2(0, 0, G1_ST_BLOAD, );
    PH_G2(0, 1, G1_ST_AGLD, );
    PH_G2(1, 0, G1_ST_BPACK, );
    PH_G2(1, 1, , DRAIN());
  }

  // epilogue: bias + weighted atomic scatter
#pragma unroll
  for (int mf = 0; mf < 4; mf++) {
    int rl0 = wm * 64 + mf * 16 + lh * 4;
#pragma unroll
    for (int nf = 0; nf < 6; nf++) {
      int col = ct * 192 + wn * 96 + nf * 16 + lr;
      float b2v = b2[(size_t)e * H_DIM + col];
#pragma unroll
      for (int j = 0; j < 4; j++) {
        int rl = rl0 + j;
        float w = swt[rl];
        if (w != 0.f)
          atomicAdd(out + (size_t)stok[rl] * H_DIM + col, (acc[mf][nf][j] + b2v) * w);
      }
    }
  }
}

// ---------------- launch ----------------
extern "C" void kernel_launch(void* const* d_in, const int* in_sizes, int n_in,
                              void* d_out, int out_size, void* d_ws, size_t ws_size,
                              hipStream_t stream)
{
  const float* x      = (const float*)d_in[0];
  const float* norm_w = (const float*)d_in[1];
  const float* gate_w = (const float*)d_in[2];
  const float* gate_b = (const float*)d_in[3];
  const float* w1     = (const float*)d_in[4];
  const float* b1     = (const float*)d_in[5];
  const float* w2     = (const float*)d_in[6];
  const float* b2     = (const float*)d_in[7];
  float* out = (float*)d_out;
  char* ws = (char*)d_ws;

  // ws layout (~141.9 MB)
  unsigned short* t_bf16  = (unsigned short*)(ws);                    // 23,592,960
  unsigned short* act     = (unsigned short*)(ws + 23592960);         // 117,964,800
  int*            topk_id = (int*)(ws + 141557760);                   // 65,536
  float*          topk_w  = (float*)(ws + 141623296);                 // 65,536
  int*            perm_tk = (int*)(ws + 141688832);                   // 81,920
  float*          perm_w  = (float*)(ws + 141770752);                 // 81,920
  int*            counts  = (int*)(ws + 141852672);                   // 64
  int*            d_off   = (int*)(ws + 141852736);                   // 68

  hipMemsetAsync(counts, 0, 64, stream);
  hipLaunchKernelGGL(k_norm_gate, dim3(T_TOK), dim3(256), 0, stream,
                     x, norm_w, gate_w, gate_b, out, t_bf16, topk_id, topk_w, counts);
  hipLaunchKernelGGL(k_offsets, dim3(1), dim3(64), 0, stream, counts, d_off);
  hipLaunchKernelGGL(k_fill, dim3(16), dim3(256), 0, stream,
                     topk_id, topk_w, counts, d_off, perm_tk, perm_w);
  hipLaunchKernelGGL(k_gemm1, dim3(G1), dim3(512), 0, stream,
                     t_bf16, w1, b1, perm_tk, d_off, act);
  hipLaunchKernelGGL(k_gemm2, dim3(G2), dim3(512), 0, stream,
                     act, w2, b2, perm_tk, perm_w, d_off, out);
}